// Round 11
// baseline (392.162 us; speedup 1.0000x reference)
//
#include <hip/hip_runtime.h>

#define NN 100000
#define NE 800000
#define NBUCK 196  // ceil(NN/512)
#define EPB 3125   // NE / 256 edge-blocks
#define BCAP 6144  // max edges per 512-node bucket (mean 4082)

typedef __attribute__((ext_vector_type(8))) short short8;
typedef __attribute__((ext_vector_type(4))) float f32x4;
typedef unsigned long long u64;

__device__ __forceinline__ unsigned short f2b(float x) {
  unsigned int u = __float_as_uint(x);
  u = u + 0x7fffu + ((u >> 16) & 1u);
  return (unsigned short)(u >> 16);
}
__device__ __forceinline__ float b2f(unsigned short s) {
  return __uint_as_float(((unsigned int)s) << 16);
}

// ---- weight prep: bf16 pre-swizzled W1c/W2/Wl1/Wl2 + f32 wcol table --------
__global__ __launch_bounds__(256) void wprep(
    const float* __restrict__ W1, const float* __restrict__ W2,
    const float* __restrict__ Wl1, const float* __restrict__ Wl2,
    unsigned short* __restrict__ w1p, unsigned short* __restrict__ w2p,
    unsigned short* __restrict__ wl1p, unsigned short* __restrict__ wl2p,
    float* __restrict__ wcolp) {
  int i = blockIdx.x * 256 + threadIdx.x;
  if (i < 20480) {  // W1c: 5 layers, c<64, k<64
    int l = i >> 12, r = i & 4095, c = r >> 6, k = r & 63;
    int idx = (((c * 64 + k) * 2) ^ ((c & 7) << 4)) >> 1;
    w1p[l * 4096 + idx] = f2b(W1[(l * 64 + c) * 67 + k]);
  } else if (i < 61440) {  // W2: 5 layers, c<64, k<128
    int j = i - 20480;
    int l = j >> 13, r = j & 8191, c = r >> 7, k = r & 127;
    int idx = (((c * 128 + k) * 2) ^ ((c & 7) << 4)) >> 1;
    w2p[l * 8192 + idx] = f2b(W2[(l * 64 + c) * 128 + k]);
  } else if (i < 65536) {  // Wl1: c<64, k<64
    int j = i - 61440;
    int c = j >> 6, k = j & 63;
    int idx = (((c * 64 + k) * 2) ^ ((c & 7) << 4)) >> 1;
    wl1p[idx] = f2b(Wl1[c * 64 + k]);
  } else if (i < 67584) {  // Wl2: c<32, k<64
    int j = i - 65536;
    int c = j >> 6, k = j & 63;
    int idx = (((c * 64 + k) * 2) ^ ((c & 7) << 4)) >> 1;
    wl2p[idx] = f2b(Wl2[c * 64 + k]);
  } else if (i < 68544) {  // wcol: [5][3][64] = W1[l][f][64+j]
    int j = i - 67584;
    int l = j / 192, r = j % 192, jj = r >> 6, f = r & 63;
    wcolp[(l * 3 + jj) * 64 + f] = W1[(l * 64 + f) * 67 + 64 + jj];
  }
}

// ============ edge bucket sort (gather sequential, scatter coalesced) =======

__global__ __launch_bounds__(256) void ehist(const int* __restrict__ dst,
                                             int* __restrict__ hp) {
  __shared__ int lh[NBUCK];
  int tid = threadIdx.x;
  if (tid < NBUCK) lh[tid] = 0;
  __syncthreads();
  int e0 = blockIdx.x * EPB;
  for (int i = tid; i < EPB; i += 256) atomicAdd(&lh[dst[e0 + i] >> 9], 1);
  __syncthreads();
  if (tid < NBUCK) hp[blockIdx.x * NBUCK + tid] = lh[tid];
}

// 1-block scan: hp -> per-(block,bucket) exclusive offsets; bucket_start
__global__ void escan(int* __restrict__ hp, int* __restrict__ bucket_start) {
  __shared__ int wsum[4];
  int b = threadIdx.x;
  int running = 0;
  if (b < NBUCK) {
    for (int blk = 0; blk < 256; ++blk) {
      int t = hp[blk * NBUCK + b];
      hp[blk * NBUCK + b] = running;
      running += t;
    }
  }
  int lane = b & 63, wv = b >> 6;
  int v = running;
#pragma unroll
  for (int off = 1; off < 64; off <<= 1) {
    int t = __shfl_up(v, off);
    if (lane >= off) v += t;
  }
  if (lane == 63) wsum[wv] = v;
  __syncthreads();
  int wpre = 0;
  for (int j = 0; j < wv; ++j) wpre += wsum[j];
  int excl = v + wpre - running;
  if (b <= NBUCK) bucket_start[b] = excl;
}

// sequential gather of 5 edge arrays; packed u64 records scattered to buckets
__global__ __launch_bounds__(256) void escatter(
    const int* __restrict__ dst, const int* __restrict__ src,
    const float* __restrict__ si, const float* __restrict__ di,
    const float* __restrict__ rv, const int* __restrict__ hp,
    const int* __restrict__ bucket_start, u64* __restrict__ erec_tmp,
    unsigned short* __restrict__ lbkt) {
  __shared__ int cur[NBUCK];
  int tid = threadIdx.x;
  if (tid < NBUCK) cur[tid] = bucket_start[tid] + hp[blockIdx.x * NBUCK + tid];
  __syncthreads();
  int e0 = blockIdx.x * EPB;
  for (int i = tid; i < EPB; i += 256) {
    int e = e0 + i;
    int d = dst[e];
    int pos = atomicAdd(&cur[d >> 9], 1);
    unsigned int a = (unsigned int)fminf(si[e] * 32768.f, 32767.f);
    unsigned int b = (unsigned int)fminf(di[e] * 32768.f, 32767.f);
    unsigned int c = (unsigned int)fminf(rv[e] * 32768.f, 32767.f);
    u64 u = (u64)(src[e] & 0x1FFFF) | ((u64)a << 17) | ((u64)b << 32) |
            ((u64)c << 47);
    erec_tmp[pos] = u;
    lbkt[pos] = (unsigned short)(d & 511);
  }
}

// per bucket: CSR permutation + rowst/deg + degree-bin hist
__global__ __launch_bounds__(256) void bucket_csr(
    const unsigned short* __restrict__ lbkt, const int* __restrict__ bstart,
    const u64* __restrict__ erec_tmp, u64* __restrict__ erec,
    int* __restrict__ deg, int* __restrict__ rowst, int* __restrict__ nhp) {
  __shared__ unsigned short lb[BCAP];
  __shared__ int cnt[512];
  __shared__ int excl[512];
  __shared__ int dh[64];
  __shared__ int wsum[4];
  int b = blockIdx.x, tid = threadIdx.x;
  int s0 = bstart[b];
  int size = bstart[b + 1] - s0;
  if (size > BCAP) size = BCAP;
  cnt[2 * tid] = 0;
  cnt[2 * tid + 1] = 0;
  if (tid < 64) dh[tid] = 0;
  __syncthreads();
  for (int p = tid; p < size; p += 256) {
    unsigned short v = lbkt[s0 + p];
    lb[p] = v;
    atomicAdd(&cnt[v], 1);
  }
  __syncthreads();
  int a = cnt[2 * tid], c = cnt[2 * tid + 1];
  int ps = a + c;
  int lane = tid & 63, wv = tid >> 6;
  int v = ps;
#pragma unroll
  for (int off = 1; off < 64; off <<= 1) {
    int t = __shfl_up(v, off);
    if (lane >= off) v += t;
  }
  if (lane == 63) wsum[wv] = v;
  __syncthreads();
  int wpre = 0;
  for (int j = 0; j < wv; ++j) wpre += wsum[j];
  int ex = v + wpre - ps;  // exclusive over node pairs
  excl[2 * tid] = ex;
  excl[2 * tid + 1] = ex + a;
  int n0 = b << 9;
#pragma unroll
  for (int j = 0; j < 2; ++j) {
    int i = 2 * tid + j;
    int n = n0 + i;
    if (n < NN) {
      int d = j ? c : a;
      deg[n] = d;
      rowst[n] = s0 + (j ? ex + a : ex);
      atomicAdd(&dh[(d < 63) ? d : 63], 1);
    }
  }
  cnt[2 * tid] = 0;
  cnt[2 * tid + 1] = 0;
  __syncthreads();
  for (int p = tid; p < size; p += 256) {
    int ld = lb[p];
    int pos = excl[ld] + atomicAdd(&cnt[ld], 1);
    erec[s0 + pos] = erec_tmp[s0 + p];
  }
  if (tid < 64) nhp[b * 64 + tid] = dh[tid];
}

// 1-block scan of degree-bin partial hists
__global__ void nscan(int* __restrict__ nhp, int* __restrict__ nbin_start) {
  int b = threadIdx.x;
  int running = 0;
  for (int blk = 0; blk < NBUCK; ++blk) {
    int t = nhp[blk * 64 + b];
    nhp[blk * 64 + b] = running;
    running += t;
  }
  int v = running, s = running;
#pragma unroll
  for (int off = 1; off < 64; off <<= 1) {
    int t = __shfl_up(s, off);
    if (b >= off) s += t;
  }
  nbin_start[b] = s - v;
}

// emit degree-sorted packed node records: {row_start:20 | cnt:10 | n:17}
__global__ __launch_bounds__(256) void nscatter(
    const int* __restrict__ deg, const int* __restrict__ rowst,
    const int* __restrict__ nhp, const int* __restrict__ nbin_start,
    u64* __restrict__ smeta) {
  __shared__ int cur[64];
  int tid = threadIdx.x;
  if (tid < 64) cur[tid] = nbin_start[tid] + nhp[blockIdx.x * 64 + tid];
  __syncthreads();
  int n0 = blockIdx.x * 512;
#pragma unroll
  for (int j = 0; j < 2; ++j) {
    int n = n0 + tid + j * 256;
    if (n < NN) {
      int d = deg[n];
      int pos = atomicAdd(&cur[(d < 63) ? d : 63], 1);
      smeta[pos] = (u64)(unsigned)rowst[n] | ((u64)(unsigned)d << 20) |
                   ((u64)(unsigned)n << 30);
    }
  }
}

// ------- aggregation: quarter-wave per 2 nodes; 3-deep rec / 2-deep row ----

__global__ __launch_bounds__(256) void aggregate(
    const unsigned short* __restrict__ H1, const u64* __restrict__ smeta,
    const u64* __restrict__ erec, const float* __restrict__ wcolp,
    unsigned short* __restrict__ hNs) {
  __shared__ float wcol[3][64];
  int tid = threadIdx.x;
  if (tid < 192) ((float*)wcol)[tid] = wcolp[tid];
  __syncthreads();
  int l = tid & 63;
  int fl = l & 15, f0 = fl * 4;
  int qbase = (blockIdx.x * 16 + (tid >> 4)) * 2;
  float wa[4], wb[4], wc[4];
#pragma unroll
  for (int j = 0; j < 4; ++j) {
    wa[j] = wcol[0][f0 + j];
    wb[j] = wcol[1][f0 + j];
    wc[j] = wcol[2][f0 + j];
  }
  const float q = 1.f / 32768.f;
#pragma unroll 1
  for (int t = 0; t < 2; ++t) {
    int qidx = qbase + t;
    if (qidx >= NN) return;
    u64 sm = smeta[qidx];
    int s0 = (int)(sm & 0xFFFFF);
    int cnt = (int)((sm >> 20) & 0x3FF);
    int n = (int)(sm >> 30);
    float invd = 1.f / fmaxf((float)cnt, 1.f);
    float acc[4] = {0.f, 0.f, 0.f, 0.f};
    u64 r0 = 0, r1 = 0, r2 = 0;
    ushort4 h0 = make_ushort4(0, 0, 0, 0), h1 = h0;
    if (cnt > 0) {
      r0 = erec[s0];
      h0 = *(const ushort4*)&H1[(size_t)(r0 & 0x1FFFF) * 64 + f0];
    }
    if (cnt > 1) {
      r1 = erec[s0 + 1];
      h1 = *(const ushort4*)&H1[(size_t)(r1 & 0x1FFFF) * 64 + f0];
    }
    if (cnt > 2) r2 = erec[s0 + 2];
    for (int k = 0; k < cnt; ++k) {
      u64 r3 = 0;
      if (k + 3 < cnt) r3 = erec[s0 + k + 3];
      ushort4 h2 = make_ushort4(0, 0, 0, 0);
      if (k + 2 < cnt)
        h2 = *(const ushort4*)&H1[(size_t)(r2 & 0x1FFFF) * 64 + f0];
      float hx[4] = {b2f(h0.x), b2f(h0.y), b2f(h0.z), b2f(h0.w)};
      float si = (float)((unsigned)(r0 >> 17) & 0x7FFF) * q;
      float di = (float)((unsigned)(r0 >> 32) & 0x7FFF) * q;
      float rv = (float)((unsigned)(r0 >> 47) & 0x7FFF) * q;
#pragma unroll
      for (int j = 0; j < 4; ++j) {
        float vv = hx[j] + si * wa[j] + di * wb[j] + rv * wc[j];
        acc[j] += (vv >= 0.f) ? vv : 0.01f * vv;
      }
      r0 = r1;
      r1 = r2;
      r2 = r3;
      h0 = h1;
      h1 = h2;
    }
    ushort4 o = make_ushort4(f2b(acc[0] * invd), f2b(acc[1] * invd),
                             f2b(acc[2] * invd), f2b(acc[3] * invd));
    *(ushort4*)&hNs[(size_t)n * 64 + f0] = o;
  }
}

// ---------------- fused GEMM helpers ----------------

__device__ __forceinline__ void stageP(const unsigned short* __restrict__ src,
                                       unsigned short* lds, int n, int tid,
                                       int nt) {
  for (int idx = tid; idx * 8 < n; idx += nt)
    *(short8*)&lds[idx * 8] = *(const short8*)&src[idx * 8];
}
__device__ __forceinline__ short8 ldW(const unsigned short* lds, int K, int c,
                                      int k) {
  int byte = (c * K + k) * 2;
  byte ^= ((c & 7) << 4);
  return *(const short8*)((const char*)lds + byte);
}
__device__ __forceinline__ void stH(unsigned short* ht, int row, int col,
                                    unsigned short v) {
  int byte = row * 128 + col * 2;
  byte ^= ((row & 7) << 4);
  *(unsigned short*)((char*)ht + byte) = v;
}
__device__ __forceinline__ short8 ldH(const unsigned short* ht, int row,
                                      int k) {
  int byte = row * 128 + k * 2;
  byte ^= ((row & 7) << 4);
  return *(const short8*)((const char*)ht + byte);
}

// fused0: h0 = emb[gate]; H1 = h0 @ W1c^T (256 thr, 128 rows)
__global__ __launch_bounds__(256) void fused0(
    const int* __restrict__ gate, const float* __restrict__ emb,
    const unsigned short* __restrict__ w1p, unsigned short* __restrict__ hout,
    unsigned short* __restrict__ H1out) {
  __shared__ __align__(16) unsigned short W1l[64 * 64];
  int tid = threadIdx.x;
  stageP(w1p, W1l, 64 * 64, tid, 256);
  __syncthreads();
  int w = tid >> 6, l = tid & 63, r16 = l & 15, kg = l >> 4;
  int row_base = blockIdx.x * 128 + w * 32;
  f32x4 acc[2][4];
#pragma unroll
  for (int rt = 0; rt < 2; ++rt)
#pragma unroll
    for (int ct = 0; ct < 4; ++ct) {
      f32x4 z = {0.f, 0.f, 0.f, 0.f};
      acc[rt][ct] = z;
    }
#pragma unroll
  for (int rt = 0; rt < 2; ++rt) {
    int arow = row_base + rt * 16 + r16;
    short8 a0 = {0, 0, 0, 0, 0, 0, 0, 0};
    short8 a1 = {0, 0, 0, 0, 0, 0, 0, 0};
    if (arow < NN) {
      int g = gate[arow];
      const float* ep = &emb[g * 64];
      float4 e0 = *(const float4*)&ep[kg * 8];
      float4 e1 = *(const float4*)&ep[kg * 8 + 4];
      float4 e2 = *(const float4*)&ep[32 + kg * 8];
      float4 e3 = *(const float4*)&ep[32 + kg * 8 + 4];
      a0[0] = (short)f2b(e0.x); a0[1] = (short)f2b(e0.y);
      a0[2] = (short)f2b(e0.z); a0[3] = (short)f2b(e0.w);
      a0[4] = (short)f2b(e1.x); a0[5] = (short)f2b(e1.y);
      a0[6] = (short)f2b(e1.z); a0[7] = (short)f2b(e1.w);
      a1[0] = (short)f2b(e2.x); a1[1] = (short)f2b(e2.y);
      a1[2] = (short)f2b(e2.z); a1[3] = (short)f2b(e2.w);
      a1[4] = (short)f2b(e3.x); a1[5] = (short)f2b(e3.y);
      a1[6] = (short)f2b(e3.z); a1[7] = (short)f2b(e3.w);
      *(short8*)&hout[(size_t)arow * 64 + kg * 8] = a0;
      *(short8*)&hout[(size_t)arow * 64 + 32 + kg * 8] = a1;
    }
#pragma unroll
    for (int ct = 0; ct < 4; ++ct) {
      int c = ct * 16 + r16;
      acc[rt][ct] = __builtin_amdgcn_mfma_f32_16x16x32_bf16(
          a0, ldW(W1l, 64, c, kg * 8), acc[rt][ct], 0, 0, 0);
      acc[rt][ct] = __builtin_amdgcn_mfma_f32_16x16x32_bf16(
          a1, ldW(W1l, 64, c, 32 + kg * 8), acc[rt][ct], 0, 0, 0);
    }
  }
#pragma unroll
  for (int rt = 0; rt < 2; ++rt)
#pragma unroll
    for (int ct = 0; ct < 4; ++ct) {
      int col = ct * 16 + r16;
#pragma unroll
      for (int i = 0; i < 4; ++i) {
        int row = row_base + rt * 16 + kg * 4 + i;
        if (row < NN) H1out[(size_t)row * 64 + col] = f2b(acc[rt][ct][i]);
      }
    }
}

// fused_mid: hnew = relu(h@W2a + hNs@W2b + b2); H1 = hnew@W1n_c^T
// 512 threads / 8 waves; each wave owns 16 rows of the 128-row tile.
__global__ __launch_bounds__(512) void fused_mid(
    const unsigned short* h, const unsigned short* __restrict__ hNs,
    const unsigned short* __restrict__ w2p, const float* __restrict__ b2,
    const unsigned short* __restrict__ w1np, unsigned short* hout,
    unsigned short* __restrict__ H1out) {
  __shared__ __align__(16) unsigned short W2l[64 * 128];
  __shared__ __align__(16) unsigned short W1l[64 * 64];
  __shared__ __align__(16) unsigned short ht[128 * 64];
  int tid = threadIdx.x;
  stageP(w2p, W2l, 64 * 128, tid, 512);
  stageP(w1np, W1l, 64 * 64, tid, 512);
  __syncthreads();
  int w = tid >> 6, l = tid & 63, r16 = l & 15, kg = l >> 4;
  int row_base = blockIdx.x * 128 + w * 16;
  int arow = row_base + r16;
  short8 z8 = {0, 0, 0, 0, 0, 0, 0, 0};
  short8 a0 = z8, a1 = z8, c0 = z8, c1 = z8;
  if (arow < NN) {
    a0 = *(const short8*)&h[(size_t)arow * 64 + kg * 8];
    a1 = *(const short8*)&h[(size_t)arow * 64 + 32 + kg * 8];
    c0 = *(const short8*)&hNs[(size_t)arow * 64 + kg * 8];
    c1 = *(const short8*)&hNs[(size_t)arow * 64 + 32 + kg * 8];
  }
  f32x4 acc[4];
#pragma unroll
  for (int ct = 0; ct < 4; ++ct) {
    f32x4 z = {0.f, 0.f, 0.f, 0.f};
    acc[ct] = z;
  }
#pragma unroll
  for (int ct = 0; ct < 4; ++ct) {
    int c = ct * 16 + r16;
    acc[ct] = __builtin_amdgcn_mfma_f32_16x16x32_bf16(
        a0, ldW(W2l, 128, c, kg * 8), acc[ct], 0, 0, 0);
    acc[ct] = __builtin_amdgcn_mfma_f32_16x16x32_bf16(
        a1, ldW(W2l, 128, c, 32 + kg * 8), acc[ct], 0, 0, 0);
    acc[ct] = __builtin_amdgcn_mfma_f32_16x16x32_bf16(
        c0, ldW(W2l, 128, c, 64 + kg * 8), acc[ct], 0, 0, 0);
    acc[ct] = __builtin_amdgcn_mfma_f32_16x16x32_bf16(
        c1, ldW(W2l, 128, c, 96 + kg * 8), acc[ct], 0, 0, 0);
  }
#pragma unroll
  for (int ct = 0; ct < 4; ++ct) {
    int col = ct * 16 + r16;
    float bv = b2[col];
#pragma unroll
    for (int i = 0; i < 4; ++i) {
      int lrow = w * 16 + kg * 4 + i;
      float v = acc[ct][i] + bv;
      v = fmaxf(v, 0.f);
      stH(ht, lrow, col, f2b(v));
    }
  }
  __syncthreads();
  f32x4 acc2[4];
#pragma unroll
  for (int ct = 0; ct < 4; ++ct) {
    f32x4 z = {0.f, 0.f, 0.f, 0.f};
    acc2[ct] = z;
  }
  {
    int lrow = w * 16 + r16;
    short8 b0 = ldH(ht, lrow, kg * 8);
    short8 b1 = ldH(ht, lrow, 32 + kg * 8);
    if (arow < NN) {
      *(short8*)&hout[(size_t)arow * 64 + kg * 8] = b0;
      *(short8*)&hout[(size_t)arow * 64 + 32 + kg * 8] = b1;
    }
#pragma unroll
    for (int ct = 0; ct < 4; ++ct) {
      int c = ct * 16 + r16;
      acc2[ct] = __builtin_amdgcn_mfma_f32_16x16x32_bf16(
          b0, ldW(W1l, 64, c, kg * 8), acc2[ct], 0, 0, 0);
      acc2[ct] = __builtin_amdgcn_mfma_f32_16x16x32_bf16(
          b1, ldW(W1l, 64, c, 32 + kg * 8), acc2[ct], 0, 0, 0);
    }
  }
#pragma unroll
  for (int ct = 0; ct < 4; ++ct) {
    int col = ct * 16 + r16;
#pragma unroll
    for (int i = 0; i < 4; ++i) {
      int row = row_base + kg * 4 + i;
      if (row < NN) H1out[(size_t)row * 64 + col] = f2b(acc2[ct][i]);
    }
  }
}

// fused_final: h5 = relu(h@W2a+hNs@W2b+b2); t = relu(h5@Wl1^T+bl1);
//              out = t@Wl2^T + bl2 (f32) — 512 threads / 8 waves
__global__ __launch_bounds__(512) void fused_final(
    const unsigned short* __restrict__ h, const unsigned short* __restrict__ hNs,
    const unsigned short* __restrict__ w2p, const float* __restrict__ b2,
    const unsigned short* __restrict__ wl1p, const float* __restrict__ bl1,
    const unsigned short* __restrict__ wl2p, const float* __restrict__ bl2,
    float* __restrict__ out) {
  __shared__ __align__(16) unsigned short W2l[64 * 128];
  __shared__ __align__(16) unsigned short Al[64 * 64];
  __shared__ __align__(16) unsigned short Bl[32 * 64];
  __shared__ __align__(16) unsigned short ht[128 * 64];
  int tid = threadIdx.x;
  stageP(w2p, W2l, 64 * 128, tid, 512);
  stageP(wl1p, Al, 64 * 64, tid, 512);
  stageP(wl2p, Bl, 32 * 64, tid, 512);
  __syncthreads();
  int w = tid >> 6, l = tid & 63, r16 = l & 15, kg = l >> 4;
  int row_base = blockIdx.x * 128 + w * 16;
  int arow = row_base + r16;
  short8 z8 = {0, 0, 0, 0, 0, 0, 0, 0};
  short8 a0 = z8, a1 = z8, c0 = z8, c1 = z8;
  if (arow < NN) {
    a0 = *(const short8*)&h[(size_t)arow * 64 + kg * 8];
    a1 = *(const short8*)&h[(size_t)arow * 64 + 32 + kg * 8];
    c0 = *(const short8*)&hNs[(size_t)arow * 64 + kg * 8];
    c1 = *(const short8*)&hNs[(size_t)arow * 64 + 32 + kg * 8];
  }
  f32x4 acc[4];
#pragma unroll
  for (int ct = 0; ct < 4; ++ct) {
    f32x4 z = {0.f, 0.f, 0.f, 0.f};
    acc[ct] = z;
  }
#pragma unroll
  for (int ct = 0; ct < 4; ++ct) {
    int c = ct * 16 + r16;
    acc[ct] = __builtin_amdgcn_mfma_f32_16x16x32_bf16(
        a0, ldW(W2l, 128, c, kg * 8), acc[ct], 0, 0, 0);
    acc[ct] = __builtin_amdgcn_mfma_f32_16x16x32_bf16(
        a1, ldW(W2l, 128, c, 32 + kg * 8), acc[ct], 0, 0, 0);
    acc[ct] = __builtin_amdgcn_mfma_f32_16x16x32_bf16(
        c0, ldW(W2l, 128, c, 64 + kg * 8), acc[ct], 0, 0, 0);
    acc[ct] = __builtin_amdgcn_mfma_f32_16x16x32_bf16(
        c1, ldW(W2l, 128, c, 96 + kg * 8), acc[ct], 0, 0, 0);
  }
#pragma unroll
  for (int ct = 0; ct < 4; ++ct) {
    int col = ct * 16 + r16;
    float bv = b2[col];
#pragma unroll
    for (int i = 0; i < 4; ++i) {
      int lrow = w * 16 + kg * 4 + i;
      float v = acc[ct][i] + bv;
      v = fmaxf(v, 0.f);
      stH(ht, lrow, col, f2b(v));
    }
  }
  __syncthreads();
  f32x4 acc2[4];
#pragma unroll
  for (int ct = 0; ct < 4; ++ct) {
    f32x4 z = {0.f, 0.f, 0.f, 0.f};
    acc2[ct] = z;
  }
  {
    int lrow = w * 16 + r16;
    short8 b0 = ldH(ht, lrow, kg * 8);
    short8 b1 = ldH(ht, lrow, 32 + kg * 8);
#pragma unroll
    for (int ct = 0; ct < 4; ++ct) {
      int c = ct * 16 + r16;
      acc2[ct] = __builtin_amdgcn_mfma_f32_16x16x32_bf16(
          b0, ldW(Al, 64, c, kg * 8), acc2[ct], 0, 0, 0);
      acc2[ct] = __builtin_amdgcn_mfma_f32_16x16x32_bf16(
          b1, ldW(Al, 64, c, 32 + kg * 8), acc2[ct], 0, 0, 0);
    }
  }
  __syncthreads();
#pragma unroll
  for (int ct = 0; ct < 4; ++ct) {
    int col = ct * 16 + r16;
    float bv = bl1[col];
#pragma unroll
    for (int i = 0; i < 4; ++i) {
      int lrow = w * 16 + kg * 4 + i;
      float v = acc2[ct][i] + bv;
      v = fmaxf(v, 0.f);
      stH(ht, lrow, col, f2b(v));
    }
  }
  __syncthreads();
  f32x4 acc3[2];
#pragma unroll
  for (int ct = 0; ct < 2; ++ct) {
    f32x4 z = {0.f, 0.f, 0.f, 0.f};
    acc3[ct] = z;
  }
  {
    int lrow = w * 16 + r16;
    short8 b0 = ldH(ht, lrow, kg * 8);
    short8 b1 = ldH(ht, lrow, 32 + kg * 8);
#pragma unroll
    for (int ct = 0; ct < 2; ++ct) {
      int c = ct * 16 + r16;
      acc3[ct] = __builtin_amdgcn_mfma_f32_16x16x32_bf16(
          b0, ldW(Bl, 64, c, kg * 8), acc3[ct], 0, 0, 0);
      acc3[ct] = __builtin_amdgcn_mfma_f32_16x16x32_bf16(
          b1, ldW(Bl, 64, c, 32 + kg * 8), acc3[ct], 0, 0, 0);
    }
  }
#pragma unroll
  for (int ct = 0; ct < 2; ++ct) {
    int col = ct * 16 + r16;
    float bv = bl2[col];
#pragma unroll
    for (int i = 0; i < 4; ++i) {
      int row = row_base + kg * 4 + i;
      if (row < NN) out[(size_t)row * 32 + col] = acc3[ct][i] + bv;
    }
  }
}

// ---------------- launcher ----------------

extern "C" void kernel_launch(void* const* d_in, const int* in_sizes, int n_in,
                              void* d_out, int out_size, void* d_ws, size_t ws_size,
                              hipStream_t stream) {
  const int* gate = (const int*)d_in[0];
  const int* src = (const int*)d_in[1];
  const int* dst = (const int*)d_in[2];
  const float* src_idx = (const float*)d_in[3];
  const float* dst_idx = (const float*)d_in[4];
  const float* rev = (const float*)d_in[5];
  const float* emb = (const float*)d_in[6];
  const float* W1 = (const float*)d_in[7];
  const float* W2 = (const float*)d_in[8];
  const float* b2 = (const float*)d_in[9];
  const float* Wl1 = (const float*)d_in[10];
  const float* bl1 = (const float*)d_in[11];
  const float* Wl2 = (const float*)d_in[12];
  const float* bl2 = (const float*)d_in[13];
  float* out = (float*)d_out;

  char* ws = (char*)d_ws;
  unsigned short* h = (unsigned short*)(ws + 0);           // 12.8 MB
  unsigned short* lbkt = (unsigned short*)(ws + 0);        // aliases h (build)
  unsigned short* H1 = (unsigned short*)(ws + 12800000);   // 12.8 MB
  unsigned short* hNs = (unsigned short*)(ws + 25600000);  // 12.8 MB
  u64* erec_tmp = (u64*)(ws + 25600000);                   // aliases hNs, 6.4 MB
  u64* erec = (u64*)(ws + 38400000);                       // 6.4 MB
  u64* smeta = (u64*)(ws + 51200000);                      // 0.8 MB
  int* rowst = (int*)(ws + 52800000);                      // 0.4 MB
  int* deg = (int*)(ws + 53200000);                        // 0.4 MB
  int* hp = (int*)(ws + 53600000);                         // 256*196*4
  int* bucket_start = (int*)(ws + 53810000);               // 197 ints
  int* nhp = (int*)(ws + 53820000);                        // 196*64*4
  int* nbin_start = (int*)(ws + 53880000);                 // 64 ints
  unsigned short* w1p = (unsigned short*)(ws + 53900000);  // 40960 B
  unsigned short* w2p = (unsigned short*)(ws + 53950000);  // 81920 B
  unsigned short* wl1p = (unsigned short*)(ws + 54040000); // 8192 B
  unsigned short* wl2p = (unsigned short*)(ws + 54050000); // 4096 B
  float* wcolp = (float*)(ws + 54060000);                  // 3840 B

  wprep<<<268, 256, 0, stream>>>(W1, W2, Wl1, Wl2, w1p, w2p, wl1p, wl2p, wcolp);
  ehist<<<256, 256, 0, stream>>>(dst, hp);
  escan<<<1, 256, 0, stream>>>(hp, bucket_start);
  escatter<<<256, 256, 0, stream>>>(dst, src, src_idx, dst_idx, rev, hp,
                                    bucket_start, erec_tmp, lbkt);
  bucket_csr<<<NBUCK, 256, 0, stream>>>(lbkt, bucket_start, erec_tmp, erec,
                                        deg, rowst, nhp);
  nscan<<<1, 64, 0, stream>>>(nhp, nbin_start);
  nscatter<<<NBUCK, 256, 0, stream>>>(deg, rowst, nhp, nbin_start, smeta);

  fused0<<<782, 256, 0, stream>>>(gate, emb, w1p, h, H1);
  for (int i = 0; i < 5; ++i) {
    aggregate<<<3125, 256, 0, stream>>>(H1, smeta, erec, wcolp + i * 192, hNs);
    if (i < 4)
      fused_mid<<<782, 512, 0, stream>>>(h, hNs, w2p + i * 8192, b2 + i * 64,
                                         w1p + (i + 1) * 4096, h, H1);
  }
  fused_final<<<782, 512, 0, stream>>>(h, hNs, w2p + 4 * 8192, b2 + 4 * 64,
                                       wl1p, bl1, wl2p, bl2, out);
}

// Round 12
// 352.976 us; speedup vs baseline: 1.1110x; 1.1110x over previous
//
#include <hip/hip_runtime.h>

#define NN 100000
#define NE 800000
#define NBUCK 196  // ceil(NN/512)
#define EPB 3125   // NE / 256 edge-blocks
#define BCAP 6144  // max edges per 512-node bucket (mean 4082)

typedef __attribute__((ext_vector_type(8))) short short8;
typedef __attribute__((ext_vector_type(4))) float f32x4;
typedef unsigned long long u64;

__device__ __forceinline__ unsigned short f2b(float x) {
  unsigned int u = __float_as_uint(x);
  u = u + 0x7fffu + ((u >> 16) & 1u);
  return (unsigned short)(u >> 16);
}
__device__ __forceinline__ float b2f(unsigned short s) {
  return __uint_as_float(((unsigned int)s) << 16);
}

// ---- weight prep: bf16 pre-swizzled W1c/W2/Wl1/Wl2 + f32 wcol table --------
__global__ __launch_bounds__(256) void wprep(
    const float* __restrict__ W1, const float* __restrict__ W2,
    const float* __restrict__ Wl1, const float* __restrict__ Wl2,
    unsigned short* __restrict__ w1p, unsigned short* __restrict__ w2p,
    unsigned short* __restrict__ wl1p, unsigned short* __restrict__ wl2p,
    float* __restrict__ wcolp) {
  int i = blockIdx.x * 256 + threadIdx.x;
  if (i < 20480) {  // W1c: 5 layers, c<64, k<64
    int l = i >> 12, r = i & 4095, c = r >> 6, k = r & 63;
    int idx = (((c * 64 + k) * 2) ^ ((c & 7) << 4)) >> 1;
    w1p[l * 4096 + idx] = f2b(W1[(l * 64 + c) * 67 + k]);
  } else if (i < 61440) {  // W2: 5 layers, c<64, k<128
    int j = i - 20480;
    int l = j >> 13, r = j & 8191, c = r >> 7, k = r & 127;
    int idx = (((c * 128 + k) * 2) ^ ((c & 7) << 4)) >> 1;
    w2p[l * 8192 + idx] = f2b(W2[(l * 64 + c) * 128 + k]);
  } else if (i < 65536) {  // Wl1: c<64, k<64
    int j = i - 61440;
    int c = j >> 6, k = j & 63;
    int idx = (((c * 64 + k) * 2) ^ ((c & 7) << 4)) >> 1;
    wl1p[idx] = f2b(Wl1[c * 64 + k]);
  } else if (i < 67584) {  // Wl2: c<32, k<64
    int j = i - 65536;
    int c = j >> 6, k = j & 63;
    int idx = (((c * 64 + k) * 2) ^ ((c & 7) << 4)) >> 1;
    wl2p[idx] = f2b(Wl2[c * 64 + k]);
  } else if (i < 68544) {  // wcol: [5][3][64] = W1[l][f][64+j]
    int j = i - 67584;
    int l = j / 192, r = j % 192, jj = r >> 6, f = r & 63;
    wcolp[(l * 3 + jj) * 64 + f] = W1[(l * 64 + f) * 67 + 64 + jj];
  }
}

// ============ edge bucket sort (gather sequential, scatter coalesced) =======

__global__ __launch_bounds__(256) void ehist(const int* __restrict__ dst,
                                             int* __restrict__ hp) {
  __shared__ int lh[NBUCK];
  int tid = threadIdx.x;
  if (tid < NBUCK) lh[tid] = 0;
  __syncthreads();
  int e0 = blockIdx.x * EPB;
  for (int i = tid; i < EPB; i += 256) atomicAdd(&lh[dst[e0 + i] >> 9], 1);
  __syncthreads();
  if (tid < NBUCK) hp[blockIdx.x * NBUCK + tid] = lh[tid];
}

// 1-block scan: hp -> per-(block,bucket) exclusive offsets; bucket_start
__global__ void escan(int* __restrict__ hp, int* __restrict__ bucket_start) {
  __shared__ int wsum[4];
  int b = threadIdx.x;
  int running = 0;
  if (b < NBUCK) {
    for (int blk = 0; blk < 256; ++blk) {
      int t = hp[blk * NBUCK + b];
      hp[blk * NBUCK + b] = running;
      running += t;
    }
  }
  int lane = b & 63, wv = b >> 6;
  int v = running;
#pragma unroll
  for (int off = 1; off < 64; off <<= 1) {
    int t = __shfl_up(v, off);
    if (lane >= off) v += t;
  }
  if (lane == 63) wsum[wv] = v;
  __syncthreads();
  int wpre = 0;
  for (int j = 0; j < wv; ++j) wpre += wsum[j];
  int excl = v + wpre - running;
  if (b <= NBUCK) bucket_start[b] = excl;
}

// sequential gather of 5 edge arrays; packed u64 records scattered to buckets
__global__ __launch_bounds__(256) void escatter(
    const int* __restrict__ dst, const int* __restrict__ src,
    const float* __restrict__ si, const float* __restrict__ di,
    const float* __restrict__ rv, const int* __restrict__ hp,
    const int* __restrict__ bucket_start, u64* __restrict__ erec_tmp,
    unsigned short* __restrict__ lbkt) {
  __shared__ int cur[NBUCK];
  int tid = threadIdx.x;
  if (tid < NBUCK) cur[tid] = bucket_start[tid] + hp[blockIdx.x * NBUCK + tid];
  __syncthreads();
  int e0 = blockIdx.x * EPB;
  for (int i = tid; i < EPB; i += 256) {
    int e = e0 + i;
    int d = dst[e];
    int pos = atomicAdd(&cur[d >> 9], 1);
    unsigned int a = (unsigned int)fminf(si[e] * 32768.f, 32767.f);
    unsigned int b = (unsigned int)fminf(di[e] * 32768.f, 32767.f);
    unsigned int c = (unsigned int)fminf(rv[e] * 32768.f, 32767.f);
    u64 u = (u64)(src[e] & 0x1FFFF) | ((u64)a << 17) | ((u64)b << 32) |
            ((u64)c << 47);
    erec_tmp[pos] = u;
    lbkt[pos] = (unsigned short)(d & 511);
  }
}

// per bucket: CSR permutation + rowst/deg + degree-bin hist
__global__ __launch_bounds__(256) void bucket_csr(
    const unsigned short* __restrict__ lbkt, const int* __restrict__ bstart,
    const u64* __restrict__ erec_tmp, u64* __restrict__ erec,
    int* __restrict__ deg, int* __restrict__ rowst, int* __restrict__ nhp) {
  __shared__ unsigned short lb[BCAP];
  __shared__ int cnt[512];
  __shared__ int excl[512];
  __shared__ int dh[64];
  __shared__ int wsum[4];
  int b = blockIdx.x, tid = threadIdx.x;
  int s0 = bstart[b];
  int size = bstart[b + 1] - s0;
  if (size > BCAP) size = BCAP;
  cnt[2 * tid] = 0;
  cnt[2 * tid + 1] = 0;
  if (tid < 64) dh[tid] = 0;
  __syncthreads();
  for (int p = tid; p < size; p += 256) {
    unsigned short v = lbkt[s0 + p];
    lb[p] = v;
    atomicAdd(&cnt[v], 1);
  }
  __syncthreads();
  int a = cnt[2 * tid], c = cnt[2 * tid + 1];
  int ps = a + c;
  int lane = tid & 63, wv = tid >> 6;
  int v = ps;
#pragma unroll
  for (int off = 1; off < 64; off <<= 1) {
    int t = __shfl_up(v, off);
    if (lane >= off) v += t;
  }
  if (lane == 63) wsum[wv] = v;
  __syncthreads();
  int wpre = 0;
  for (int j = 0; j < wv; ++j) wpre += wsum[j];
  int ex = v + wpre - ps;  // exclusive over node pairs
  excl[2 * tid] = ex;
  excl[2 * tid + 1] = ex + a;
  int n0 = b << 9;
#pragma unroll
  for (int j = 0; j < 2; ++j) {
    int i = 2 * tid + j;
    int n = n0 + i;
    if (n < NN) {
      int d = j ? c : a;
      deg[n] = d;
      rowst[n] = s0 + (j ? ex + a : ex);
      atomicAdd(&dh[(d < 63) ? d : 63], 1);
    }
  }
  cnt[2 * tid] = 0;
  cnt[2 * tid + 1] = 0;
  __syncthreads();
  for (int p = tid; p < size; p += 256) {
    int ld = lb[p];
    int pos = excl[ld] + atomicAdd(&cnt[ld], 1);
    erec[s0 + pos] = erec_tmp[s0 + p];
  }
  if (tid < 64) nhp[b * 64 + tid] = dh[tid];
}

// 1-block scan of degree-bin partial hists
__global__ void nscan(int* __restrict__ nhp, int* __restrict__ nbin_start) {
  int b = threadIdx.x;
  int running = 0;
  for (int blk = 0; blk < NBUCK; ++blk) {
    int t = nhp[blk * 64 + b];
    nhp[blk * 64 + b] = running;
    running += t;
  }
  int v = running, s = running;
#pragma unroll
  for (int off = 1; off < 64; off <<= 1) {
    int t = __shfl_up(s, off);
    if (b >= off) s += t;
  }
  nbin_start[b] = s - v;
}

// emit degree-sorted packed node records: {row_start:20 | cnt:10 | n:17}
__global__ __launch_bounds__(256) void nscatter(
    const int* __restrict__ deg, const int* __restrict__ rowst,
    const int* __restrict__ nhp, const int* __restrict__ nbin_start,
    u64* __restrict__ smeta) {
  __shared__ int cur[64];
  int tid = threadIdx.x;
  if (tid < 64) cur[tid] = nbin_start[tid] + nhp[blockIdx.x * 64 + tid];
  __syncthreads();
  int n0 = blockIdx.x * 512;
#pragma unroll
  for (int j = 0; j < 2; ++j) {
    int n = n0 + tid + j * 256;
    if (n < NN) {
      int d = deg[n];
      int pos = atomicAdd(&cur[(d < 63) ? d : 63], 1);
      smeta[pos] = (u64)(unsigned)rowst[n] | ((u64)(unsigned)d << 20) |
                   ((u64)(unsigned)n << 30);
    }
  }
}

// ------- aggregation: quarter-wave per node; 3-deep rec / 2-deep row pipe ---

__global__ __launch_bounds__(256) void aggregate(
    const unsigned short* __restrict__ H1, const u64* __restrict__ smeta,
    const u64* __restrict__ erec, const float* __restrict__ wcolp,
    unsigned short* __restrict__ hNs) {
  __shared__ float wcol[3][64];
  int tid = threadIdx.x;
  if (tid < 192) ((float*)wcol)[tid] = wcolp[tid];
  __syncthreads();
  int l = tid & 63;
  int fl = l & 15, f0 = fl * 4;
  int qidx = blockIdx.x * 16 + (tid >> 4);
  float wa[4], wb[4], wc[4];
#pragma unroll
  for (int j = 0; j < 4; ++j) {
    wa[j] = wcol[0][f0 + j];
    wb[j] = wcol[1][f0 + j];
    wc[j] = wcol[2][f0 + j];
  }
  if (qidx >= NN) return;
  u64 sm = smeta[qidx];
  int s0 = (int)(sm & 0xFFFFF);
  int cnt = (int)((sm >> 20) & 0x3FF);
  int n = (int)(sm >> 30);
  float invd = 1.f / fmaxf((float)cnt, 1.f);
  float acc[4] = {0.f, 0.f, 0.f, 0.f};
  u64 r0 = 0, r1 = 0, r2 = 0;
  ushort4 h0 = make_ushort4(0, 0, 0, 0), h1 = h0;
  if (cnt > 0) {
    r0 = erec[s0];
    h0 = *(const ushort4*)&H1[(size_t)(r0 & 0x1FFFF) * 64 + f0];
  }
  if (cnt > 1) {
    r1 = erec[s0 + 1];
    h1 = *(const ushort4*)&H1[(size_t)(r1 & 0x1FFFF) * 64 + f0];
  }
  if (cnt > 2) r2 = erec[s0 + 2];
  const float q = 1.f / 32768.f;
  for (int k = 0; k < cnt; ++k) {
    u64 r3 = 0;
    if (k + 3 < cnt) r3 = erec[s0 + k + 3];
    ushort4 h2 = make_ushort4(0, 0, 0, 0);
    if (k + 2 < cnt)
      h2 = *(const ushort4*)&H1[(size_t)(r2 & 0x1FFFF) * 64 + f0];
    float hx[4] = {b2f(h0.x), b2f(h0.y), b2f(h0.z), b2f(h0.w)};
    float si = (float)((unsigned)(r0 >> 17) & 0x7FFF) * q;
    float di = (float)((unsigned)(r0 >> 32) & 0x7FFF) * q;
    float rv = (float)((unsigned)(r0 >> 47) & 0x7FFF) * q;
#pragma unroll
    for (int j = 0; j < 4; ++j) {
      float vv = hx[j] + si * wa[j] + di * wb[j] + rv * wc[j];
      acc[j] += (vv >= 0.f) ? vv : 0.01f * vv;
    }
    r0 = r1;
    r1 = r2;
    r2 = r3;
    h0 = h1;
    h1 = h2;
  }
  ushort4 o = make_ushort4(f2b(acc[0] * invd), f2b(acc[1] * invd),
                           f2b(acc[2] * invd), f2b(acc[3] * invd));
  *(ushort4*)&hNs[(size_t)n * 64 + f0] = o;
}

// ---------------- fused GEMM helpers ----------------

__device__ __forceinline__ void stageP(const unsigned short* __restrict__ src,
                                       unsigned short* lds, int n, int tid,
                                       int nt) {
  for (int idx = tid; idx * 8 < n; idx += nt)
    *(short8*)&lds[idx * 8] = *(const short8*)&src[idx * 8];
}
__device__ __forceinline__ short8 ldW(const unsigned short* lds, int K, int c,
                                      int k) {
  int byte = (c * K + k) * 2;
  byte ^= ((c & 7) << 4);
  return *(const short8*)((const char*)lds + byte);
}
__device__ __forceinline__ void stH(unsigned short* ht, int row, int col,
                                    unsigned short v) {
  int byte = row * 128 + col * 2;
  byte ^= ((row & 7) << 4);
  *(unsigned short*)((char*)ht + byte) = v;
}
__device__ __forceinline__ short8 ldH(const unsigned short* ht, int row,
                                      int k) {
  int byte = row * 128 + k * 2;
  byte ^= ((row & 7) << 4);
  return *(const short8*)((const char*)ht + byte);
}

// fused0: h0 = emb[gate]; H1 = h0 @ W1c^T (256 thr, 128 rows)
__global__ __launch_bounds__(256) void fused0(
    const int* __restrict__ gate, const float* __restrict__ emb,
    const unsigned short* __restrict__ w1p, unsigned short* __restrict__ hout,
    unsigned short* __restrict__ H1out) {
  __shared__ __align__(16) unsigned short W1l[64 * 64];
  int tid = threadIdx.x;
  stageP(w1p, W1l, 64 * 64, tid, 256);
  __syncthreads();
  int w = tid >> 6, l = tid & 63, r16 = l & 15, kg = l >> 4;
  int row_base = blockIdx.x * 128 + w * 32;
  f32x4 acc[2][4];
#pragma unroll
  for (int rt = 0; rt < 2; ++rt)
#pragma unroll
    for (int ct = 0; ct < 4; ++ct) {
      f32x4 z = {0.f, 0.f, 0.f, 0.f};
      acc[rt][ct] = z;
    }
#pragma unroll
  for (int rt = 0; rt < 2; ++rt) {
    int arow = row_base + rt * 16 + r16;
    short8 a0 = {0, 0, 0, 0, 0, 0, 0, 0};
    short8 a1 = {0, 0, 0, 0, 0, 0, 0, 0};
    if (arow < NN) {
      int g = gate[arow];
      const float* ep = &emb[g * 64];
      float4 e0 = *(const float4*)&ep[kg * 8];
      float4 e1 = *(const float4*)&ep[kg * 8 + 4];
      float4 e2 = *(const float4*)&ep[32 + kg * 8];
      float4 e3 = *(const float4*)&ep[32 + kg * 8 + 4];
      a0[0] = (short)f2b(e0.x); a0[1] = (short)f2b(e0.y);
      a0[2] = (short)f2b(e0.z); a0[3] = (short)f2b(e0.w);
      a0[4] = (short)f2b(e1.x); a0[5] = (short)f2b(e1.y);
      a0[6] = (short)f2b(e1.z); a0[7] = (short)f2b(e1.w);
      a1[0] = (short)f2b(e2.x); a1[1] = (short)f2b(e2.y);
      a1[2] = (short)f2b(e2.z); a1[3] = (short)f2b(e2.w);
      a1[4] = (short)f2b(e3.x); a1[5] = (short)f2b(e3.y);
      a1[6] = (short)f2b(e3.z); a1[7] = (short)f2b(e3.w);
      *(short8*)&hout[(size_t)arow * 64 + kg * 8] = a0;
      *(short8*)&hout[(size_t)arow * 64 + 32 + kg * 8] = a1;
    }
#pragma unroll
    for (int ct = 0; ct < 4; ++ct) {
      int c = ct * 16 + r16;
      acc[rt][ct] = __builtin_amdgcn_mfma_f32_16x16x32_bf16(
          a0, ldW(W1l, 64, c, kg * 8), acc[rt][ct], 0, 0, 0);
      acc[rt][ct] = __builtin_amdgcn_mfma_f32_16x16x32_bf16(
          a1, ldW(W1l, 64, c, 32 + kg * 8), acc[rt][ct], 0, 0, 0);
    }
  }
#pragma unroll
  for (int rt = 0; rt < 2; ++rt)
#pragma unroll
    for (int ct = 0; ct < 4; ++ct) {
      int col = ct * 16 + r16;
#pragma unroll
      for (int i = 0; i < 4; ++i) {
        int row = row_base + rt * 16 + kg * 4 + i;
        if (row < NN) H1out[(size_t)row * 64 + col] = f2b(acc[rt][ct][i]);
      }
    }
}

// fused_mid: hnew = relu(h@W2a + hNs@W2b + b2); H1 = hnew@W1n_c^T
// 512 threads / 8 waves; each wave owns 16 rows of the 128-row tile.
__global__ __launch_bounds__(512) void fused_mid(
    const unsigned short* h, const unsigned short* __restrict__ hNs,
    const unsigned short* __restrict__ w2p, const float* __restrict__ b2,
    const unsigned short* __restrict__ w1np, unsigned short* hout,
    unsigned short* __restrict__ H1out) {
  __shared__ __align__(16) unsigned short W2l[64 * 128];
  __shared__ __align__(16) unsigned short W1l[64 * 64];
  __shared__ __align__(16) unsigned short ht[128 * 64];
  int tid = threadIdx.x;
  stageP(w2p, W2l, 64 * 128, tid, 512);
  stageP(w1np, W1l, 64 * 64, tid, 512);
  __syncthreads();
  int w = tid >> 6, l = tid & 63, r16 = l & 15, kg = l >> 4;
  int row_base = blockIdx.x * 128 + w * 16;
  int arow = row_base + r16;
  short8 z8 = {0, 0, 0, 0, 0, 0, 0, 0};
  short8 a0 = z8, a1 = z8, c0 = z8, c1 = z8;
  if (arow < NN) {
    a0 = *(const short8*)&h[(size_t)arow * 64 + kg * 8];
    a1 = *(const short8*)&h[(size_t)arow * 64 + 32 + kg * 8];
    c0 = *(const short8*)&hNs[(size_t)arow * 64 + kg * 8];
    c1 = *(const short8*)&hNs[(size_t)arow * 64 + 32 + kg * 8];
  }
  f32x4 acc[4];
#pragma unroll
  for (int ct = 0; ct < 4; ++ct) {
    f32x4 z = {0.f, 0.f, 0.f, 0.f};
    acc[ct] = z;
  }
#pragma unroll
  for (int ct = 0; ct < 4; ++ct) {
    int c = ct * 16 + r16;
    acc[ct] = __builtin_amdgcn_mfma_f32_16x16x32_bf16(
        a0, ldW(W2l, 128, c, kg * 8), acc[ct], 0, 0, 0);
    acc[ct] = __builtin_amdgcn_mfma_f32_16x16x32_bf16(
        a1, ldW(W2l, 128, c, 32 + kg * 8), acc[ct], 0, 0, 0);
    acc[ct] = __builtin_amdgcn_mfma_f32_16x16x32_bf16(
        c0, ldW(W2l, 128, c, 64 + kg * 8), acc[ct], 0, 0, 0);
    acc[ct] = __builtin_amdgcn_mfma_f32_16x16x32_bf16(
        c1, ldW(W2l, 128, c, 96 + kg * 8), acc[ct], 0, 0, 0);
  }
#pragma unroll
  for (int ct = 0; ct < 4; ++ct) {
    int col = ct * 16 + r16;
    float bv = b2[col];
#pragma unroll
    for (int i = 0; i < 4; ++i) {
      int lrow = w * 16 + kg * 4 + i;
      float v = acc[ct][i] + bv;
      v = fmaxf(v, 0.f);
      stH(ht, lrow, col, f2b(v));
    }
  }
  __syncthreads();
  f32x4 acc2[4];
#pragma unroll
  for (int ct = 0; ct < 4; ++ct) {
    f32x4 z = {0.f, 0.f, 0.f, 0.f};
    acc2[ct] = z;
  }
  {
    int lrow = w * 16 + r16;
    short8 b0 = ldH(ht, lrow, kg * 8);
    short8 b1 = ldH(ht, lrow, 32 + kg * 8);
    if (arow < NN) {
      *(short8*)&hout[(size_t)arow * 64 + kg * 8] = b0;
      *(short8*)&hout[(size_t)arow * 64 + 32 + kg * 8] = b1;
    }
#pragma unroll
    for (int ct = 0; ct < 4; ++ct) {
      int c = ct * 16 + r16;
      acc2[ct] = __builtin_amdgcn_mfma_f32_16x16x32_bf16(
          b0, ldW(W1l, 64, c, kg * 8), acc2[ct], 0, 0, 0);
      acc2[ct] = __builtin_amdgcn_mfma_f32_16x16x32_bf16(
          b1, ldW(W1l, 64, c, 32 + kg * 8), acc2[ct], 0, 0, 0);
    }
  }
#pragma unroll
  for (int ct = 0; ct < 4; ++ct) {
    int col = ct * 16 + r16;
#pragma unroll
    for (int i = 0; i < 4; ++i) {
      int row = row_base + kg * 4 + i;
      if (row < NN) H1out[(size_t)row * 64 + col] = f2b(acc2[ct][i]);
    }
  }
}

// fused_final: h5 = relu(h@W2a+hNs@W2b+b2); t = relu(h5@Wl1^T+bl1);
//              out = t@Wl2^T + bl2 (f32) — 512 threads / 8 waves
__global__ __launch_bounds__(512) void fused_final(
    const unsigned short* __restrict__ h, const unsigned short* __restrict__ hNs,
    const unsigned short* __restrict__ w2p, const float* __restrict__ b2,
    const unsigned short* __restrict__ wl1p, const float* __restrict__ bl1,
    const unsigned short* __restrict__ wl2p, const float* __restrict__ bl2,
    float* __restrict__ out) {
  __shared__ __align__(16) unsigned short W2l[64 * 128];
  __shared__ __align__(16) unsigned short Al[64 * 64];
  __shared__ __align__(16) unsigned short Bl[32 * 64];
  __shared__ __align__(16) unsigned short ht[128 * 64];
  int tid = threadIdx.x;
  stageP(w2p, W2l, 64 * 128, tid, 512);
  stageP(wl1p, Al, 64 * 64, tid, 512);
  stageP(wl2p, Bl, 32 * 64, tid, 512);
  __syncthreads();
  int w = tid >> 6, l = tid & 63, r16 = l & 15, kg = l >> 4;
  int row_base = blockIdx.x * 128 + w * 16;
  int arow = row_base + r16;
  short8 z8 = {0, 0, 0, 0, 0, 0, 0, 0};
  short8 a0 = z8, a1 = z8, c0 = z8, c1 = z8;
  if (arow < NN) {
    a0 = *(const short8*)&h[(size_t)arow * 64 + kg * 8];
    a1 = *(const short8*)&h[(size_t)arow * 64 + 32 + kg * 8];
    c0 = *(const short8*)&hNs[(size_t)arow * 64 + kg * 8];
    c1 = *(const short8*)&hNs[(size_t)arow * 64 + 32 + kg * 8];
  }
  f32x4 acc[4];
#pragma unroll
  for (int ct = 0; ct < 4; ++ct) {
    f32x4 z = {0.f, 0.f, 0.f, 0.f};
    acc[ct] = z;
  }
#pragma unroll
  for (int ct = 0; ct < 4; ++ct) {
    int c = ct * 16 + r16;
    acc[ct] = __builtin_amdgcn_mfma_f32_16x16x32_bf16(
        a0, ldW(W2l, 128, c, kg * 8), acc[ct], 0, 0, 0);
    acc[ct] = __builtin_amdgcn_mfma_f32_16x16x32_bf16(
        a1, ldW(W2l, 128, c, 32 + kg * 8), acc[ct], 0, 0, 0);
    acc[ct] = __builtin_amdgcn_mfma_f32_16x16x32_bf16(
        c0, ldW(W2l, 128, c, 64 + kg * 8), acc[ct], 0, 0, 0);
    acc[ct] = __builtin_amdgcn_mfma_f32_16x16x32_bf16(
        c1, ldW(W2l, 128, c, 96 + kg * 8), acc[ct], 0, 0, 0);
  }
#pragma unroll
  for (int ct = 0; ct < 4; ++ct) {
    int col = ct * 16 + r16;
    float bv = b2[col];
#pragma unroll
    for (int i = 0; i < 4; ++i) {
      int lrow = w * 16 + kg * 4 + i;
      float v = acc[ct][i] + bv;
      v = fmaxf(v, 0.f);
      stH(ht, lrow, col, f2b(v));
    }
  }
  __syncthreads();
  f32x4 acc2[4];
#pragma unroll
  for (int ct = 0; ct < 4; ++ct) {
    f32x4 z = {0.f, 0.f, 0.f, 0.f};
    acc2[ct] = z;
  }
  {
    int lrow = w * 16 + r16;
    short8 b0 = ldH(ht, lrow, kg * 8);
    short8 b1 = ldH(ht, lrow, 32 + kg * 8);
#pragma unroll
    for (int ct = 0; ct < 4; ++ct) {
      int c = ct * 16 + r16;
      acc2[ct] = __builtin_amdgcn_mfma_f32_16x16x32_bf16(
          b0, ldW(Al, 64, c, kg * 8), acc2[ct], 0, 0, 0);
      acc2[ct] = __builtin_amdgcn_mfma_f32_16x16x32_bf16(
          b1, ldW(Al, 64, c, 32 + kg * 8), acc2[ct], 0, 0, 0);
    }
  }
  __syncthreads();
#pragma unroll
  for (int ct = 0; ct < 4; ++ct) {
    int col = ct * 16 + r16;
    float bv = bl1[col];
#pragma unroll
    for (int i = 0; i < 4; ++i) {
      int lrow = w * 16 + kg * 4 + i;
      float v = acc2[ct][i] + bv;
      v = fmaxf(v, 0.f);
      stH(ht, lrow, col, f2b(v));
    }
  }
  __syncthreads();
  f32x4 acc3[2];
#pragma unroll
  for (int ct = 0; ct < 2; ++ct) {
    f32x4 z = {0.f, 0.f, 0.f, 0.f};
    acc3[ct] = z;
  }
  {
    int lrow = w * 16 + r16;
    short8 b0 = ldH(ht, lrow, kg * 8);
    short8 b1 = ldH(ht, lrow, 32 + kg * 8);
#pragma unroll
    for (int ct = 0; ct < 2; ++ct) {
      int c = ct * 16 + r16;
      acc3[ct] = __builtin_amdgcn_mfma_f32_16x16x32_bf16(
          b0, ldW(Bl, 64, c, kg * 8), acc3[ct], 0, 0, 0);
      acc3[ct] = __builtin_amdgcn_mfma_f32_16x16x32_bf16(
          b1, ldW(Bl, 64, c, 32 + kg * 8), acc3[ct], 0, 0, 0);
    }
  }
#pragma unroll
  for (int ct = 0; ct < 2; ++ct) {
    int col = ct * 16 + r16;
    float bv = bl2[col];
#pragma unroll
    for (int i = 0; i < 4; ++i) {
      int row = row_base + kg * 4 + i;
      if (row < NN) out[(size_t)row * 32 + col] = acc3[ct][i] + bv;
    }
  }
}

// ---------------- launcher ----------------

extern "C" void kernel_launch(void* const* d_in, const int* in_sizes, int n_in,
                              void* d_out, int out_size, void* d_ws, size_t ws_size,
                              hipStream_t stream) {
  const int* gate = (const int*)d_in[0];
  const int* src = (const int*)d_in[1];
  const int* dst = (const int*)d_in[2];
  const float* src_idx = (const float*)d_in[3];
  const float* dst_idx = (const float*)d_in[4];
  const float* rev = (const float*)d_in[5];
  const float* emb = (const float*)d_in[6];
  const float* W1 = (const float*)d_in[7];
  const float* W2 = (const float*)d_in[8];
  const float* b2 = (const float*)d_in[9];
  const float* Wl1 = (const float*)d_in[10];
  const float* bl1 = (const float*)d_in[11];
  const float* Wl2 = (const float*)d_in[12];
  const float* bl2 = (const float*)d_in[13];
  float* out = (float*)d_out;

  char* ws = (char*)d_ws;
  unsigned short* h = (unsigned short*)(ws + 0);           // 12.8 MB
  unsigned short* lbkt = (unsigned short*)(ws + 0);        // aliases h (build)
  unsigned short* H1 = (unsigned short*)(ws + 12800000);   // 12.8 MB
  unsigned short* hNs = (unsigned short*)(ws + 25600000);  // 12.8 MB
  u64* erec_tmp = (u64*)(ws + 25600000);                   // aliases hNs, 6.4 MB
  u64* erec = (u64*)(ws + 38400000);                       // 6.4 MB
  u64* smeta = (u64*)(ws + 51200000);                      // 0.8 MB
  int* rowst = (int*)(ws + 52800000);                      // 0.4 MB
  int* deg = (int*)(ws + 53200000);                        // 0.4 MB
  int* hp = (int*)(ws + 53600000);                         // 256*196*4
  int* bucket_start = (int*)(ws + 53810000);               // 197 ints
  int* nhp = (int*)(ws + 53820000);                        // 196*64*4
  int* nbin_start = (int*)(ws + 53880000);                 // 64 ints
  unsigned short* w1p = (unsigned short*)(ws + 53900000);  // 40960 B
  unsigned short* w2p = (unsigned short*)(ws + 53950000);  // 81920 B
  unsigned short* wl1p = (unsigned short*)(ws + 54040000); // 8192 B
  unsigned short* wl2p = (unsigned short*)(ws + 54050000); // 4096 B
  float* wcolp = (float*)(ws + 54060000);                  // 3840 B

  wprep<<<268, 256, 0, stream>>>(W1, W2, Wl1, Wl2, w1p, w2p, wl1p, wl2p, wcolp);
  ehist<<<256, 256, 0, stream>>>(dst, hp);
  escan<<<1, 256, 0, stream>>>(hp, bucket_start);
  escatter<<<256, 256, 0, stream>>>(dst, src, src_idx, dst_idx, rev, hp,
                                    bucket_start, erec_tmp, lbkt);
  bucket_csr<<<NBUCK, 256, 0, stream>>>(lbkt, bucket_start, erec_tmp, erec,
                                        deg, rowst, nhp);
  nscan<<<1, 64, 0, stream>>>(nhp, nbin_start);
  nscatter<<<NBUCK, 256, 0, stream>>>(deg, rowst, nhp, nbin_start, smeta);

  fused0<<<782, 256, 0, stream>>>(gate, emb, w1p, h, H1);
  for (int i = 0; i < 5; ++i) {
    aggregate<<<6250, 256, 0, stream>>>(H1, smeta, erec, wcolp + i * 192, hNs);
    if (i < 4)
      fused_mid<<<782, 512, 0, stream>>>(h, hNs, w2p + i * 8192, b2 + i * 64,
                                         w1p + (i + 1) * 4096, h, H1);
  }
  fused_final<<<782, 512, 0, stream>>>(h, hNs, w2p + 4 * 8192, b2 + 4 * 64,
                                       wl1p, bl1, wl2p, bl2, out);
}